// Round 1
// baseline (3060.594 us; speedup 1.0000x reference)
//
#include <hip/hip_runtime.h>
#include <cstdint>
#include <cstddef>

#define N_NODES_C 50000
#define N_EDGES_C 1600000
#define N_GRAPHS_C 128
#define EDGE_DIM_C 43
#define IN_DIM_C 35
#define HDIM_C 128
#define NODES_PER_WG 8

__device__ __forceinline__ float fast_tanh(float x) {
    float xc = fminf(9.0f, fmaxf(-9.0f, x));
    float t = __expf(2.0f * xc);
    return (t - 1.0f) * __builtin_amdgcn_rcpf(t + 1.0f);
}

// ---------------- CSR build ----------------

__global__ __launch_bounds__(256) void hist_kernel(const int* __restrict__ src,
                                                   int* __restrict__ cnt) {
    int i = blockIdx.x * 256 + threadIdx.x;
    if (i < N_EDGES_C) atomicAdd(&cnt[src[i]], 1);
}

__global__ __launch_bounds__(1024) void scan_kernel(const int* __restrict__ cnt,
                                                    int* __restrict__ rowptr,
                                                    int* __restrict__ work) {
    __shared__ int wsum[16];
    __shared__ int carry_s;
    int t = threadIdx.x;
    int lane = t & 63, wid = t >> 6;
    if (t == 0) carry_s = 0;
    __syncthreads();
    for (int base = 0; base < N_NODES_C; base += 1024) {
        int i = base + t;
        int v = (i < N_NODES_C) ? cnt[i] : 0;
        int x = v;
        #pragma unroll
        for (int off = 1; off < 64; off <<= 1) {
            int y = __shfl_up(x, off, 64);
            if (lane >= off) x += y;
        }
        if (lane == 63) wsum[wid] = x;
        __syncthreads();
        if (wid == 0) {
            int wv = (lane < 16) ? wsum[lane] : 0;
            #pragma unroll
            for (int off = 1; off < 16; off <<= 1) {
                int y = __shfl_up(wv, off, 64);
                if (lane >= off) wv += y;
            }
            if (lane < 16) wsum[lane] = wv;
        }
        __syncthreads();
        int blockoff = carry_s + (wid ? wsum[wid - 1] : 0);
        int excl = blockoff + x - v;
        if (i < N_NODES_C) { rowptr[i] = excl; work[i] = excl; }
        int total = wsum[15];
        __syncthreads();
        if (t == 0) carry_s += total;
        __syncthreads();
    }
    if (t == 0) rowptr[N_NODES_C] = carry_s;
}

__global__ __launch_bounds__(256) void scatter_kernel(const int* __restrict__ src,
                                                      int* __restrict__ work,
                                                      int* __restrict__ perm) {
    int i = blockIdx.x * 256 + threadIdx.x;
    if (i < N_EDGES_C) {
        int s = src[i];
        int pos = atomicAdd(&work[s], 1);
        perm[pos] = i;
    }
}

__global__ __launch_bounds__(256) void graph_bounds(const int* __restrict__ batch,
                                                    int* __restrict__ grp) {
    int t = blockIdx.x * 256 + threadIdx.x;
    if (t > N_GRAPHS_C) return;
    int lo = 0, hi = N_NODES_C;
    while (lo < hi) {
        int mid = (lo + hi) >> 1;
        if (batch[mid] < t) lo = mid + 1; else hi = mid;
    }
    grp[t] = lo;
}

// ---------------- Node GEMM (Base = A@Wx.T+bn ; Root = tanh(A@Wr.T+br)) ----------------
// grid.x tiles of 64 nodes, grid.y in {0: Base, 1: Root}

#define BKN 32
__global__ __launch_bounds__(256) void node_gemm(
    const float* __restrict__ A, int K,
    const float* __restrict__ Wn, int ldn, const float* __restrict__ bn,
    const float* __restrict__ Wr, const float* __restrict__ br,
    float* __restrict__ Base, float* __restrict__ Root)
{
    __shared__ float At[BKN][64];
    __shared__ float Bw[BKN][128];
    int t = threadIdx.x;
    int z = blockIdx.y;
    const float* W = z ? Wr : Wn;
    int ldW = z ? K : ldn;
    const float* bias = z ? br : bn;
    float* Out = z ? Root : Base;

    int m0 = blockIdx.x * 64;
    int tn4 = (t % 32) * 4;
    int tm8 = (t / 32) * 8;
    float acc[8][4];
    #pragma unroll
    for (int a = 0; a < 8; a++)
        #pragma unroll
        for (int b = 0; b < 4; b++) acc[a][b] = 0.0f;

    int nkc = (K + BKN - 1) / BKN;
    for (int c = 0; c < nkc; c++) {
        int kc = c * BKN;
        // A tile: m_l = t%64, kg = t/64, 8 k's each
        {
            int m_l = t % 64;
            int kg = t / 64;
            int m = m0 + m_l;
            #pragma unroll
            for (int ii = 0; ii < 8; ii++) {
                int kk = kg * 8 + ii;
                int k = kc + kk;
                float v = 0.0f;
                if (m < N_NODES_C && k < K) v = A[(size_t)m * K + k];
                At[kk][m_l] = v;
            }
        }
        // B tile: j = t%128, kg2 = t/128, 16 k's each
        {
            int j = t % 128;
            int kg2 = t / 128;
            #pragma unroll
            for (int ii = 0; ii < 16; ii++) {
                int kk = kg2 * 16 + ii;
                int k = kc + kk;
                float v = 0.0f;
                if (k < K) v = W[(size_t)j * ldW + k];
                Bw[kk][j] = v;
            }
        }
        __syncthreads();
        #pragma unroll
        for (int kk = 0; kk < BKN; kk++) {
            float a[8], b[4];
            #pragma unroll
            for (int mi = 0; mi < 8; mi++) a[mi] = At[kk][tm8 + mi];
            #pragma unroll
            for (int ni = 0; ni < 4; ni++) b[ni] = Bw[kk][tn4 + ni];
            #pragma unroll
            for (int mi = 0; mi < 8; mi++)
                #pragma unroll
                for (int ni = 0; ni < 4; ni++)
                    acc[mi][ni] = fmaf(a[mi], b[ni], acc[mi][ni]);
        }
        __syncthreads();
    }

    float4 bv = *(const float4*)&bias[tn4];
    #pragma unroll
    for (int mi = 0; mi < 8; mi++) {
        int m = m0 + tm8 + mi;
        if (m < N_NODES_C) {
            float4 o;
            o.x = acc[mi][0] + bv.x;
            o.y = acc[mi][1] + bv.y;
            o.z = acc[mi][2] + bv.z;
            o.w = acc[mi][3] + bv.w;
            if (z) { o.x = fast_tanh(o.x); o.y = fast_tanh(o.y); o.z = fast_tanh(o.z); o.w = fast_tanh(o.w); }
            *(float4*)&Out[(size_t)m * HDIM_C + tn4] = o;
        }
    }
}

// ---------------- Fused edge conv ----------------
// thread j (0..127) = channel j; We row in VGPRs; ea via uniform scalar loads.

__global__ __launch_bounds__(128) void edge_conv(
    const float* __restrict__ Base, const float* __restrict__ Root,
    const float* __restrict__ EA, const int* __restrict__ perm,
    const int* __restrict__ rowptr, const float* __restrict__ Wfull,
    int colOff, int ldW, float* __restrict__ Hout)
{
    int j = threadIdx.x;
    float w[EDGE_DIM_C];
    const float* wr = Wfull + (size_t)j * ldW + colOff;
    #pragma unroll
    for (int k = 0; k < EDGE_DIM_C; k++) w[k] = wr[k];

    int n0 = blockIdx.x * NODES_PER_WG;
    int n1 = n0 + NODES_PER_WG;
    if (n1 > N_NODES_C) n1 = N_NODES_C;

    for (int n = n0; n < n1; n++) {
        float base = Base[(size_t)n * HDIM_C + j];
        int is = __builtin_amdgcn_readfirstlane(rowptr[n]);
        int ie = __builtin_amdgcn_readfirstlane(rowptr[n + 1]);
        float acc = 0.0f;
        if (is < ie) {
            int e = __builtin_amdgcn_readfirstlane(perm[is]);
            for (int i = is; i < ie; i++) {
                int e_nxt = (i + 1 < ie) ? __builtin_amdgcn_readfirstlane(perm[i + 1]) : e;
                const float* pe = EA + (size_t)e * EDGE_DIM_C;
                float s0 = base, s1 = 0.0f, s2 = 0.0f, s3 = 0.0f;
                #pragma unroll
                for (int k = 0; k < 40; k += 4) {
                    s0 = fmaf(w[k],     pe[k],     s0);
                    s1 = fmaf(w[k + 1], pe[k + 1], s1);
                    s2 = fmaf(w[k + 2], pe[k + 2], s2);
                    s3 = fmaf(w[k + 3], pe[k + 3], s3);
                }
                s0 = fmaf(w[40], pe[40], s0);
                s1 = fmaf(w[41], pe[41], s1);
                s2 = fmaf(w[42], pe[42], s2);
                acc += fast_tanh((s0 + s1) + (s2 + s3));
                e = e_nxt;
            }
        }
        Hout[(size_t)n * HDIM_C + j] = Root[(size_t)n * HDIM_C + j] + acc;
    }
}

// ---------------- Gate MLP: 128 -> 64 -> 32 -> 1 ----------------

__global__ __launch_bounds__(64) void gate_kernel(
    const float* __restrict__ h,
    const float* __restrict__ Wg1, const float* __restrict__ bg1,
    const float* __restrict__ Wg2, const float* __restrict__ bg2,
    const float* __restrict__ Wg3, const float* __restrict__ bg3,
    float* __restrict__ gate)
{
    int n = blockIdx.x;
    int t = threadIdx.x;
    const float* hp = h + (size_t)n * HDIM_C;
    __shared__ float g1[64];
    __shared__ float g2[32];
    {
        float s = bg1[t];
        const float* wr = Wg1 + (size_t)t * 128;
        #pragma unroll 8
        for (int k = 0; k < 128; k++) s = fmaf(wr[k], hp[k], s);
        g1[t] = fmaxf(s, 0.0f);
    }
    __syncthreads();
    if (t < 32) {
        float s = bg2[t];
        const float* wr = Wg2 + (size_t)t * 64;
        #pragma unroll 8
        for (int k = 0; k < 64; k++) s = fmaf(wr[k], g1[k], s);
        g2[t] = fmaxf(s, 0.0f);
    }
    __syncthreads();
    if (t < 32) {
        float p = Wg3[t] * g2[t];
        #pragma unroll
        for (int off = 16; off >= 1; off >>= 1) p += __shfl_down(p, off, 32);
        if (t == 0) gate[n] = p + bg3[0];
    }
}

// ---------------- Per-graph softmax + attention + embedding ----------------

__global__ __launch_bounds__(256) void graph_attn(
    const float* __restrict__ gate, const int* __restrict__ grp,
    const float* __restrict__ h3, float* __restrict__ att_out,
    float* __restrict__ emb)
{
    int g = blockIdx.x;
    int t = threadIdx.x;
    int s = grp[g], e = grp[g + 1];
    __shared__ float red[256];
    __shared__ float attb[256];

    float m = -3.4e38f;
    for (int i = s + t; i < e; i += 256) m = fmaxf(m, gate[i]);
    red[t] = m;
    __syncthreads();
    #pragma unroll
    for (int off = 128; off >= 1; off >>= 1) {
        if (t < off) red[t] = fmaxf(red[t], red[t + off]);
        __syncthreads();
    }
    m = red[0];
    __syncthreads();

    float sum = 0.0f;
    for (int i = s + t; i < e; i += 256) sum += __expf(gate[i] - m);
    red[t] = sum;
    __syncthreads();
    #pragma unroll
    for (int off = 128; off >= 1; off >>= 1) {
        if (t < off) red[t] += red[t + off];
        __syncthreads();
    }
    float scale = 1.0f / (red[0] + 1e-16f);
    __syncthreads();

    int j = t & 127;
    int half = t >> 7;
    float acc = 0.0f;
    for (int base = s; base < e; base += 256) {
        int i = base + t;
        float a = 0.0f;
        if (i < e) {
            a = __expf(gate[i] - m) * scale;
            att_out[i] = a;
        }
        attb[t] = a;
        __syncthreads();
        int cnt = e - base; if (cnt > 256) cnt = 256;
        for (int r = half; r < cnt; r += 2)
            acc = fmaf(attb[r], h3[(size_t)(base + r) * HDIM_C + j], acc);
        __syncthreads();
    }
    red[t] = acc;
    __syncthreads();
    if (t < 128) emb[(size_t)g * 128 + t] = red[t] + red[t + 128];
}

// ---------------- Final MLP: [emb(128) u_soap(64) u_dimer(64)] -> 256 -> 128 -> 64 -> 4(+sum) ----------------

__global__ __launch_bounds__(256) void final_mlp(
    const float* __restrict__ emb, const float* __restrict__ us, const float* __restrict__ ud,
    const float* __restrict__ Wl1, const float* __restrict__ bl1,
    const float* __restrict__ Wl2, const float* __restrict__ bl2,
    const float* __restrict__ Wl3, const float* __restrict__ bl3,
    const float* __restrict__ Wl, const float* __restrict__ bl,
    float* __restrict__ out5)
{
    int g = blockIdx.x;
    int t = threadIdx.x;
    __shared__ float e2[256], o1[256], o2[128], o3[64], o4[4];
    if (t < 128) e2[t] = emb[(size_t)g * 128 + t];
    else if (t < 192) e2[t] = us[(size_t)g * 64 + (t - 128)];
    else e2[t] = ud[(size_t)g * 64 + (t - 192)];
    __syncthreads();
    {
        float s = bl1[t];
        const float* wr = Wl1 + (size_t)t * 256;
        #pragma unroll 8
        for (int k = 0; k < 256; k++) s = fmaf(wr[k], e2[k], s);
        o1[t] = fmaxf(s, 0.0f);
    }
    __syncthreads();
    if (t < 128) {
        float s = bl2[t];
        const float* wr = Wl2 + (size_t)t * 256;
        #pragma unroll 8
        for (int k = 0; k < 256; k++) s = fmaf(wr[k], o1[k], s);
        o2[t] = fmaxf(s, 0.0f);
    }
    __syncthreads();
    if (t < 64) {
        float s = bl3[t];
        const float* wr = Wl3 + (size_t)t * 128;
        #pragma unroll 8
        for (int k = 0; k < 128; k++) s = fmaf(wr[k], o2[k], s);
        o3[t] = fmaxf(s, 0.0f);
    }
    __syncthreads();
    if (t < 4) {
        float s = bl[t];
        const float* wr = Wl + (size_t)t * 64;
        #pragma unroll 8
        for (int k = 0; k < 64; k++) s = fmaf(wr[k], o3[k], s);
        o4[t] = s;
    }
    __syncthreads();
    if (t < 5) {
        float v = (t < 4) ? o4[t] : (o4[0] + o4[1] + o4[2] + o4[3]);
        out5[(size_t)g * 5 + t] = v;
    }
}

// ---------------- launch ----------------

extern "C" void kernel_launch(void* const* d_in, const int* in_sizes, int n_in,
                              void* d_out, int out_size, void* d_ws, size_t ws_size,
                              hipStream_t stream) {
    const float* x       = (const float*)d_in[0];
    const float* ea      = (const float*)d_in[1];
    const float* u_soap  = (const float*)d_in[2];
    const float* u_dimer = (const float*)d_in[3];
    const float* W1n = (const float*)d_in[4];   const float* b1n = (const float*)d_in[5];
    const float* W1r = (const float*)d_in[6];   const float* b1r = (const float*)d_in[7];
    const float* W2n = (const float*)d_in[8];   const float* b2n = (const float*)d_in[9];
    const float* W2r = (const float*)d_in[10];  const float* b2r = (const float*)d_in[11];
    const float* W3n = (const float*)d_in[12];  const float* b3n = (const float*)d_in[13];
    const float* W3r = (const float*)d_in[14];  const float* b3r = (const float*)d_in[15];
    const float* Wg1 = (const float*)d_in[16];  const float* bg1 = (const float*)d_in[17];
    const float* Wg2 = (const float*)d_in[18];  const float* bg2 = (const float*)d_in[19];
    const float* Wg3 = (const float*)d_in[20];  const float* bg3 = (const float*)d_in[21];
    const float* Wl1 = (const float*)d_in[22];  const float* bl1 = (const float*)d_in[23];
    const float* Wl2 = (const float*)d_in[24];  const float* bl2 = (const float*)d_in[25];
    const float* Wl3 = (const float*)d_in[26];  const float* bl3 = (const float*)d_in[27];
    const float* Wl  = (const float*)d_in[28];  const float* bl  = (const float*)d_in[29];
    const int* eidx  = (const int*)d_in[30];
    const int* batch = (const int*)d_in[31];
    const int* src = eidx;  // row 0 of edge_index

    float* out5 = (float*)d_out;
    float* att  = out5 + (size_t)N_GRAPHS_C * 5;

    // workspace layout
    char* p = (char*)d_ws;
    size_t off = 0;
    auto alloc = [&](size_t bytes) -> void* {
        void* r = p + off;
        off += (bytes + 255) & ~(size_t)255;
        return r;
    };
    int* cnt    = (int*)alloc((size_t)N_NODES_C * 4);
    int* rowptr = (int*)alloc((size_t)(N_NODES_C + 1) * 4);
    int* work   = (int*)alloc((size_t)N_NODES_C * 4);
    int* perm   = (int*)alloc((size_t)N_EDGES_C * 4);
    int* grp    = (int*)alloc((size_t)(N_GRAPHS_C + 1) * 4);
    float* gate = (float*)alloc((size_t)N_NODES_C * 4);
    float* emb  = (float*)alloc((size_t)N_GRAPHS_C * 128 * 4);
    float* bufA = (float*)alloc((size_t)N_NODES_C * HDIM_C * 4);
    float* bufC = (float*)alloc((size_t)N_NODES_C * HDIM_C * 4);
    float* bufR = (float*)alloc((size_t)N_NODES_C * HDIM_C * 4);

    hipMemsetAsync(cnt, 0, (size_t)N_NODES_C * 4, stream);

    int eblocks = (N_EDGES_C + 255) / 256;
    hist_kernel<<<eblocks, 256, 0, stream>>>(src, cnt);
    scan_kernel<<<1, 1024, 0, stream>>>(cnt, rowptr, work);
    scatter_kernel<<<eblocks, 256, 0, stream>>>(src, work, perm);
    graph_bounds<<<1, 256, 0, stream>>>(batch, grp);

    dim3 ng((N_NODES_C + 63) / 64, 2);
    int ewg = (N_NODES_C + NODES_PER_WG - 1) / NODES_PER_WG;

    // layer 1: K=35, Wn ld=78, ea cols at offset 35
    node_gemm<<<ng, 256, 0, stream>>>(x, IN_DIM_C, W1n, IN_DIM_C + EDGE_DIM_C, b1n, W1r, b1r, bufA, bufR);
    edge_conv<<<ewg, 128, 0, stream>>>(bufA, bufR, ea, perm, rowptr, W1n, IN_DIM_C, IN_DIM_C + EDGE_DIM_C, bufA);
    // layer 2: K=128, Wn ld=171, offset 128
    node_gemm<<<ng, 256, 0, stream>>>(bufA, HDIM_C, W2n, HDIM_C + EDGE_DIM_C, b2n, W2r, b2r, bufC, bufR);
    edge_conv<<<ewg, 128, 0, stream>>>(bufC, bufR, ea, perm, rowptr, W2n, HDIM_C, HDIM_C + EDGE_DIM_C, bufC);
    // layer 3
    node_gemm<<<ng, 256, 0, stream>>>(bufC, HDIM_C, W3n, HDIM_C + EDGE_DIM_C, b3n, W3r, b3r, bufA, bufR);
    edge_conv<<<ewg, 128, 0, stream>>>(bufA, bufR, ea, perm, rowptr, W3n, HDIM_C, HDIM_C + EDGE_DIM_C, bufA);

    gate_kernel<<<N_NODES_C, 64, 0, stream>>>(bufA, Wg1, bg1, Wg2, bg2, Wg3, bg3, gate);
    graph_attn<<<N_GRAPHS_C, 256, 0, stream>>>(gate, grp, bufA, att, emb);
    final_mlp<<<N_GRAPHS_C, 256, 0, stream>>>(emb, u_soap, u_dimer,
                                              Wl1, bl1, Wl2, bl2, Wl3, bl3, Wl, bl, out5);
}

// Round 2
// 2014.731 us; speedup vs baseline: 1.5191x; 1.5191x over previous
//
#include <hip/hip_runtime.h>
#include <cstdint>
#include <cstddef>

#define N_NODES_C 50000
#define N_EDGES_C 1600000
#define N_GRAPHS_C 128
#define EDGE_DIM_C 43
#define IN_DIM_C 35
#define HDIM_C 128
#define MAXG_C 150000   // upper bound on #16-edge groups: N + E/16

typedef _Float16 f16x8 __attribute__((ext_vector_type(8)));
typedef float f32x4 __attribute__((ext_vector_type(4)));

__device__ __forceinline__ float fast_tanh(float x) {
    float xc = fminf(9.0f, fmaxf(-9.0f, x));
    float t = __expf(2.0f * xc);
    return (t - 1.0f) * __builtin_amdgcn_rcpf(t + 1.0f);
}

// ---------------- CSR build ----------------

__global__ __launch_bounds__(256) void hist_kernel(const int* __restrict__ src,
                                                   int* __restrict__ cnt) {
    int i = blockIdx.x * 256 + threadIdx.x;
    if (i < N_EDGES_C) atomicAdd(&cnt[src[i]], 1);
}

// dual scan: rowptr (edge CSR) and growptr (16-edge padded group index)
__global__ __launch_bounds__(1024) void scan_kernel(const int* __restrict__ cnt,
                                                    int* __restrict__ rowptr,
                                                    int* __restrict__ work,
                                                    int* __restrict__ growptr,
                                                    int* __restrict__ ngroups) {
    __shared__ int wsumA[16], wsumB[16];
    __shared__ int carryA, carryB;
    int t = threadIdx.x;
    int lane = t & 63, wid = t >> 6;
    if (t == 0) { carryA = 0; carryB = 0; }
    __syncthreads();
    for (int base = 0; base < N_NODES_C; base += 1024) {
        int i = base + t;
        int v = (i < N_NODES_C) ? cnt[i] : 0;
        int u = (v + 15) >> 4;
        int x = v, y = u;
        #pragma unroll
        for (int off = 1; off < 64; off <<= 1) {
            int xx = __shfl_up(x, off, 64);
            int yy = __shfl_up(y, off, 64);
            if (lane >= off) { x += xx; y += yy; }
        }
        if (lane == 63) { wsumA[wid] = x; wsumB[wid] = y; }
        __syncthreads();
        if (wid == 0) {
            int wa = (lane < 16) ? wsumA[lane] : 0;
            int wb = (lane < 16) ? wsumB[lane] : 0;
            #pragma unroll
            for (int off = 1; off < 16; off <<= 1) {
                int aa = __shfl_up(wa, off, 64);
                int bb = __shfl_up(wb, off, 64);
                if (lane >= off) { wa += aa; wb += bb; }
            }
            if (lane < 16) { wsumA[lane] = wa; wsumB[lane] = wb; }
        }
        __syncthreads();
        int exclA = carryA + (wid ? wsumA[wid - 1] : 0) + x - v;
        int exclB = carryB + (wid ? wsumB[wid - 1] : 0) + y - u;
        if (i < N_NODES_C) { rowptr[i] = exclA; work[i] = exclA; growptr[i] = exclB; }
        int totA = wsumA[15], totB = wsumB[15];
        __syncthreads();
        if (t == 0) { carryA += totA; carryB += totB; }
        __syncthreads();
    }
    if (t == 0) {
        rowptr[N_NODES_C] = carryA;
        growptr[N_NODES_C] = carryB;
        ngroups[0] = carryB;
    }
}

__global__ __launch_bounds__(256) void scatter_kernel(const int* __restrict__ src,
                                                      int* __restrict__ work,
                                                      int* __restrict__ perm) {
    int i = blockIdx.x * 256 + threadIdx.x;
    if (i < N_EDGES_C) {
        int s = src[i];
        int pos = atomicAdd(&work[s], 1);
        perm[pos] = i;
    }
}

__global__ __launch_bounds__(256) void graph_bounds(const int* __restrict__ batch,
                                                    int* __restrict__ grp) {
    int t = blockIdx.x * 256 + threadIdx.x;
    if (t > N_GRAPHS_C) return;
    int lo = 0, hi = N_NODES_C;
    while (lo < hi) {
        int mid = (lo + hi) >> 1;
        if (batch[mid] < t) lo = mid + 1; else hi = mid;
    }
    grp[t] = lo;
}

__global__ __launch_bounds__(256) void group_build(const int* __restrict__ rowptr,
                                                   const int* __restrict__ growptr,
                                                   int* __restrict__ gnode,
                                                   int* __restrict__ gvalid) {
    int n = blockIdx.x * 256 + threadIdx.x;
    if (n >= N_NODES_C) return;
    int g0 = growptr[n], g1 = growptr[n + 1];
    int deg = rowptr[n + 1] - rowptr[n];
    for (int g = g0; g < g1; ++g) {
        gnode[g] = n;
        int v = deg - (g - g0) * 16;
        gvalid[g] = (v > 16) ? 16 : v;
    }
}

// permute + fp32->f16 convert edge_attr into padded group layout [g][16 rows][48 k]
__global__ __launch_bounds__(256) void permute_ea(const float* __restrict__ EA,
                                                  const int* __restrict__ perm,
                                                  const int* __restrict__ rowptr,
                                                  const int* __restrict__ growptr,
                                                  const int* __restrict__ gnode,
                                                  const int* __restrict__ gvalid,
                                                  const int* __restrict__ ngroups_p,
                                                  _Float16* __restrict__ EAp) {
    int g = blockIdx.x;
    if (g >= ngroups_p[0]) return;
    int node = gnode[g];
    int valid = gvalid[g];
    int ebase = rowptr[node] + (g - growptr[node]) * 16;
    _Float16* outp = EAp + (size_t)g * 768;  // 16*48
    int t = threadIdx.x;
    #pragma unroll
    for (int it = 0; it < 3; ++it) {
        int idx = it * 256 + t;
        int r = idx / 48, k = idx - r * 48;
        float v = 0.0f;
        if (r < valid && k < EDGE_DIM_C) {
            int e = perm[ebase + r];
            v = EA[(size_t)e * EDGE_DIM_C + k];
        }
        outp[idx] = (_Float16)v;
    }
}

// ---------------- Node GEMM (Base = A@Wx.T+bn ; Root = tanh(A@Wr.T+br)) ----------------

#define BKN 32
__global__ __launch_bounds__(256) void node_gemm(
    const float* __restrict__ A, int K,
    const float* __restrict__ Wn, int ldn, const float* __restrict__ bn,
    const float* __restrict__ Wr, const float* __restrict__ br,
    float* __restrict__ Base, float* __restrict__ Root)
{
    __shared__ float At[BKN][64];
    __shared__ float Bw[BKN][128];
    int t = threadIdx.x;
    int z = blockIdx.y;
    const float* W = z ? Wr : Wn;
    int ldW = z ? K : ldn;
    const float* bias = z ? br : bn;
    float* Out = z ? Root : Base;

    int m0 = blockIdx.x * 64;
    int tn4 = (t % 32) * 4;
    int tm8 = (t / 32) * 8;
    float acc[8][4];
    #pragma unroll
    for (int a = 0; a < 8; a++)
        #pragma unroll
        for (int b = 0; b < 4; b++) acc[a][b] = 0.0f;

    int nkc = (K + BKN - 1) / BKN;
    for (int c = 0; c < nkc; c++) {
        int kc = c * BKN;
        {
            int m_l = t % 64;
            int kg = t / 64;
            int m = m0 + m_l;
            #pragma unroll
            for (int ii = 0; ii < 8; ii++) {
                int kk = kg * 8 + ii;
                int k = kc + kk;
                float v = 0.0f;
                if (m < N_NODES_C && k < K) v = A[(size_t)m * K + k];
                At[kk][m_l] = v;
            }
        }
        {
            int j = t % 128;
            int kg2 = t / 128;
            #pragma unroll
            for (int ii = 0; ii < 16; ii++) {
                int kk = kg2 * 16 + ii;
                int k = kc + kk;
                float v = 0.0f;
                if (k < K) v = W[(size_t)j * ldW + k];
                Bw[kk][j] = v;
            }
        }
        __syncthreads();
        #pragma unroll
        for (int kk = 0; kk < BKN; kk++) {
            float a[8], b[4];
            #pragma unroll
            for (int mi = 0; mi < 8; mi++) a[mi] = At[kk][tm8 + mi];
            #pragma unroll
            for (int ni = 0; ni < 4; ni++) b[ni] = Bw[kk][tn4 + ni];
            #pragma unroll
            for (int mi = 0; mi < 8; mi++)
                #pragma unroll
                for (int ni = 0; ni < 4; ni++)
                    acc[mi][ni] = fmaf(a[mi], b[ni], acc[mi][ni]);
        }
        __syncthreads();
    }

    float4 bv = *(const float4*)&bias[tn4];
    #pragma unroll
    for (int mi = 0; mi < 8; mi++) {
        int m = m0 + tm8 + mi;
        if (m < N_NODES_C) {
            float4 o;
            o.x = acc[mi][0] + bv.x;
            o.y = acc[mi][1] + bv.y;
            o.z = acc[mi][2] + bv.z;
            o.w = acc[mi][3] + bv.w;
            if (z) { o.x = fast_tanh(o.x); o.y = fast_tanh(o.y); o.z = fast_tanh(o.z); o.w = fast_tanh(o.w); }
            *(float4*)&Out[(size_t)m * HDIM_C + tn4] = o;
        }
    }
}

// ---------------- MFMA edge conv ----------------
// group = 16 padded edges of ONE node. Wave computes [16 edges x 128 ch] via
// 16 mfma_f32_16x16x32_f16, adds Base[node], tanh, row-reduces, atomicAdds into Hout.
// A layout: A[m=lane&15][k=quad*8+j]; B: B[k=quad*8+j][n=lane&15]; C/D: col=lane&15,row=quad*4+reg.

__global__ __launch_bounds__(256) void edge_mfma(
    const _Float16* __restrict__ EAp, const int* __restrict__ gnode,
    const int* __restrict__ gvalid, const int* __restrict__ ngroups_p,
    const float* __restrict__ Base, const float* __restrict__ Wfull,
    int colOff, int ldW, float* __restrict__ Hout)
{
    int t = threadIdx.x;
    int lane = t & 63, wid = t >> 6;
    int l15 = lane & 15, quad = lane >> 4;

    // B fragments: weights held in VGPRs for the whole kernel
    f16x8 bf[8][2];
    #pragma unroll
    for (int nt = 0; nt < 8; ++nt) {
        const float* wr = Wfull + (size_t)(nt * 16 + l15) * ldW + colOff;
        #pragma unroll
        for (int kt = 0; kt < 2; ++kt) {
            f16x8 b;
            #pragma unroll
            for (int j = 0; j < 8; ++j) {
                int k = kt * 32 + quad * 8 + j;
                float v = (k < EDGE_DIM_C) ? wr[k] : 0.0f;
                b[j] = (_Float16)v;
            }
            bf[nt][kt] = b;
        }
    }

    int ngroups = ngroups_p[0];
    int g0 = blockIdx.x * 4 + wid;
    int gstride = gridDim.x * 4;
    for (int g = g0; g < ngroups; g += gstride) {
        int node = gnode[g];
        int valid = gvalid[g];
        const _Float16* ap = EAp + (size_t)g * 768 + l15 * 48;
        f16x8 a0 = *(const f16x8*)(ap + quad * 8);
        f16x8 a1;
        if (quad < 2) a1 = *(const f16x8*)(ap + 32 + quad * 8);
        else { f16x8 z = {}; a1 = z; }

        f32x4 acc[8];
        #pragma unroll
        for (int nt = 0; nt < 8; ++nt) { f32x4 z = {0.f, 0.f, 0.f, 0.f}; acc[nt] = z; }
        #pragma unroll
        for (int nt = 0; nt < 8; ++nt) {
            acc[nt] = __builtin_amdgcn_mfma_f32_16x16x32_f16(a0, bf[nt][0], acc[nt], 0, 0, 0);
            acc[nt] = __builtin_amdgcn_mfma_f32_16x16x32_f16(a1, bf[nt][1], acc[nt], 0, 0, 0);
        }

        const float* bp = Base + (size_t)node * HDIM_C;
        int rbase = quad * 4;
        float cs[8];
        #pragma unroll
        for (int nt = 0; nt < 8; ++nt) {
            float basev = bp[nt * 16 + l15];
            float s = 0.0f;
            #pragma unroll
            for (int r = 0; r < 4; ++r) {
                float v = fast_tanh(acc[nt][r] + basev);
                s += (rbase + r < valid) ? v : 0.0f;
            }
            s += __shfl_xor(s, 16, 64);
            s += __shfl_xor(s, 32, 64);
            cs[nt] = s;
        }
        // quad q flushes n-tiles 2q and 2q+1 -> all 128 cols covered once per wave
        float v0, v1;
        if (quad == 0)      { v0 = cs[0]; v1 = cs[1]; }
        else if (quad == 1) { v0 = cs[2]; v1 = cs[3]; }
        else if (quad == 2) { v0 = cs[4]; v1 = cs[5]; }
        else                { v0 = cs[6]; v1 = cs[7]; }
        int c0 = (quad * 2) * 16 + l15;
        atomicAdd(&Hout[(size_t)node * HDIM_C + c0], v0);
        atomicAdd(&Hout[(size_t)node * HDIM_C + c0 + 16], v1);
    }
}

// ---------------- Gate MLP: 128 -> 64 -> 32 -> 1 ----------------

__global__ __launch_bounds__(64) void gate_kernel(
    const float* __restrict__ h,
    const float* __restrict__ Wg1, const float* __restrict__ bg1,
    const float* __restrict__ Wg2, const float* __restrict__ bg2,
    const float* __restrict__ Wg3, const float* __restrict__ bg3,
    float* __restrict__ gate)
{
    int n = blockIdx.x;
    int t = threadIdx.x;
    const float* hp = h + (size_t)n * HDIM_C;
    __shared__ float g1[64];
    __shared__ float g2[32];
    {
        float s = bg1[t];
        const float* wr = Wg1 + (size_t)t * 128;
        #pragma unroll 8
        for (int k = 0; k < 128; k++) s = fmaf(wr[k], hp[k], s);
        g1[t] = fmaxf(s, 0.0f);
    }
    __syncthreads();
    if (t < 32) {
        float s = bg2[t];
        const float* wr = Wg2 + (size_t)t * 64;
        #pragma unroll 8
        for (int k = 0; k < 64; k++) s = fmaf(wr[k], g1[k], s);
        g2[t] = fmaxf(s, 0.0f);
    }
    __syncthreads();
    if (t < 32) {
        float p = Wg3[t] * g2[t];
        #pragma unroll
        for (int off = 16; off >= 1; off >>= 1) p += __shfl_down(p, off, 32);
        if (t == 0) gate[n] = p + bg3[0];
    }
}

// ---------------- Per-graph softmax + attention + embedding ----------------

__global__ __launch_bounds__(256) void graph_attn(
    const float* __restrict__ gate, const int* __restrict__ grp,
    const float* __restrict__ h3, float* __restrict__ att_out,
    float* __restrict__ emb)
{
    int g = blockIdx.x;
    int t = threadIdx.x;
    int s = grp[g], e = grp[g + 1];
    __shared__ float red[256];
    __shared__ float attb[256];

    float m = -3.4e38f;
    for (int i = s + t; i < e; i += 256) m = fmaxf(m, gate[i]);
    red[t] = m;
    __syncthreads();
    #pragma unroll
    for (int off = 128; off >= 1; off >>= 1) {
        if (t < off) red[t] = fmaxf(red[t], red[t + off]);
        __syncthreads();
    }
    m = red[0];
    __syncthreads();

    float sum = 0.0f;
    for (int i = s + t; i < e; i += 256) sum += __expf(gate[i] - m);
    red[t] = sum;
    __syncthreads();
    #pragma unroll
    for (int off = 128; off >= 1; off >>= 1) {
        if (t < off) red[t] += red[t + off];
        __syncthreads();
    }
    float scale = 1.0f / (red[0] + 1e-16f);
    __syncthreads();

    int j = t & 127;
    int half = t >> 7;
    float acc = 0.0f;
    for (int base = s; base < e; base += 256) {
        int i = base + t;
        float a = 0.0f;
        if (i < e) {
            a = __expf(gate[i] - m) * scale;
            att_out[i] = a;
        }
        attb[t] = a;
        __syncthreads();
        int cnt = e - base; if (cnt > 256) cnt = 256;
        for (int r = half; r < cnt; r += 2)
            acc = fmaf(attb[r], h3[(size_t)(base + r) * HDIM_C + j], acc);
        __syncthreads();
    }
    red[t] = acc;
    __syncthreads();
    if (t < 128) emb[(size_t)g * 128 + t] = red[t] + red[t + 128];
}

// ---------------- Final MLP ----------------

__global__ __launch_bounds__(256) void final_mlp(
    const float* __restrict__ emb, const float* __restrict__ us, const float* __restrict__ ud,
    const float* __restrict__ Wl1, const float* __restrict__ bl1,
    const float* __restrict__ Wl2, const float* __restrict__ bl2,
    const float* __restrict__ Wl3, const float* __restrict__ bl3,
    const float* __restrict__ Wl, const float* __restrict__ bl,
    float* __restrict__ out5)
{
    int g = blockIdx.x;
    int t = threadIdx.x;
    __shared__ float e2[256], o1[256], o2[128], o3[64], o4[4];
    if (t < 128) e2[t] = emb[(size_t)g * 128 + t];
    else if (t < 192) e2[t] = us[(size_t)g * 64 + (t - 128)];
    else e2[t] = ud[(size_t)g * 64 + (t - 192)];
    __syncthreads();
    {
        float s = bl1[t];
        const float* wr = Wl1 + (size_t)t * 256;
        #pragma unroll 8
        for (int k = 0; k < 256; k++) s = fmaf(wr[k], e2[k], s);
        o1[t] = fmaxf(s, 0.0f);
    }
    __syncthreads();
    if (t < 128) {
        float s = bl2[t];
        const float* wr = Wl2 + (size_t)t * 256;
        #pragma unroll 8
        for (int k = 0; k < 256; k++) s = fmaf(wr[k], o1[k], s);
        o2[t] = fmaxf(s, 0.0f);
    }
    __syncthreads();
    if (t < 64) {
        float s = bl3[t];
        const float* wr = Wl3 + (size_t)t * 128;
        #pragma unroll 8
        for (int k = 0; k < 128; k++) s = fmaf(wr[k], o2[k], s);
        o3[t] = fmaxf(s, 0.0f);
    }
    __syncthreads();
    if (t < 4) {
        float s = bl[t];
        const float* wr = Wl + (size_t)t * 64;
        #pragma unroll 8
        for (int k = 0; k < 64; k++) s = fmaf(wr[k], o3[k], s);
        o4[t] = s;
    }
    __syncthreads();
    if (t < 5) {
        float v = (t < 4) ? o4[t] : (o4[0] + o4[1] + o4[2] + o4[3]);
        out5[(size_t)g * 5 + t] = v;
    }
}

// ---------------- launch ----------------

extern "C" void kernel_launch(void* const* d_in, const int* in_sizes, int n_in,
                              void* d_out, int out_size, void* d_ws, size_t ws_size,
                              hipStream_t stream) {
    const float* x       = (const float*)d_in[0];
    const float* ea      = (const float*)d_in[1];
    const float* u_soap  = (const float*)d_in[2];
    const float* u_dimer = (const float*)d_in[3];
    const float* W1n = (const float*)d_in[4];   const float* b1n = (const float*)d_in[5];
    const float* W1r = (const float*)d_in[6];   const float* b1r = (const float*)d_in[7];
    const float* W2n = (const float*)d_in[8];   const float* b2n = (const float*)d_in[9];
    const float* W2r = (const float*)d_in[10];  const float* b2r = (const float*)d_in[11];
    const float* W3n = (const float*)d_in[12];  const float* b3n = (const float*)d_in[13];
    const float* W3r = (const float*)d_in[14];  const float* b3r = (const float*)d_in[15];
    const float* Wg1 = (const float*)d_in[16];  const float* bg1 = (const float*)d_in[17];
    const float* Wg2 = (const float*)d_in[18];  const float* bg2 = (const float*)d_in[19];
    const float* Wg3 = (const float*)d_in[20];  const float* bg3 = (const float*)d_in[21];
    const float* Wl1 = (const float*)d_in[22];  const float* bl1 = (const float*)d_in[23];
    const float* Wl2 = (const float*)d_in[24];  const float* bl2 = (const float*)d_in[25];
    const float* Wl3 = (const float*)d_in[26];  const float* bl3 = (const float*)d_in[27];
    const float* Wl  = (const float*)d_in[28];  const float* bl  = (const float*)d_in[29];
    const int* eidx  = (const int*)d_in[30];
    const int* batch = (const int*)d_in[31];
    const int* src = eidx;  // row 0 of edge_index

    float* out5 = (float*)d_out;
    float* att  = out5 + (size_t)N_GRAPHS_C * 5;

    char* p = (char*)d_ws;
    size_t off = 0;
    auto alloc = [&](size_t bytes) -> void* {
        void* r = p + off;
        off += (bytes + 255) & ~(size_t)255;
        return r;
    };
    int* cnt     = (int*)alloc((size_t)N_NODES_C * 4);
    int* rowptr  = (int*)alloc((size_t)(N_NODES_C + 1) * 4);
    int* growptr = (int*)alloc((size_t)(N_NODES_C + 1) * 4);
    int* work    = (int*)alloc((size_t)N_NODES_C * 4);
    int* perm    = (int*)alloc((size_t)N_EDGES_C * 4);
    int* grp     = (int*)alloc((size_t)(N_GRAPHS_C + 1) * 4);
    int* ngroups = (int*)alloc(256);
    int* gnode   = (int*)alloc((size_t)MAXG_C * 4);
    int* gvalid  = (int*)alloc((size_t)MAXG_C * 4);
    float* gate  = (float*)alloc((size_t)N_NODES_C * 4);
    float* emb   = (float*)alloc((size_t)N_GRAPHS_C * 128 * 4);
    float* bufBase = (float*)alloc((size_t)N_NODES_C * HDIM_C * 4);
    float* bufA    = (float*)alloc((size_t)N_NODES_C * HDIM_C * 4);
    float* bufB    = (float*)alloc((size_t)N_NODES_C * HDIM_C * 4);
    _Float16* EAp  = (_Float16*)alloc((size_t)MAXG_C * 768 * 2);

    hipMemsetAsync(cnt, 0, (size_t)N_NODES_C * 4, stream);

    int eblocks = (N_EDGES_C + 255) / 256;
    hist_kernel<<<eblocks, 256, 0, stream>>>(src, cnt);
    scan_kernel<<<1, 1024, 0, stream>>>(cnt, rowptr, work, growptr, ngroups);
    scatter_kernel<<<eblocks, 256, 0, stream>>>(src, work, perm);
    graph_bounds<<<1, 256, 0, stream>>>(batch, grp);
    group_build<<<(N_NODES_C + 255) / 256, 256, 0, stream>>>(rowptr, growptr, gnode, gvalid);
    permute_ea<<<MAXG_C, 256, 0, stream>>>(ea, perm, rowptr, growptr, gnode, gvalid, ngroups, EAp);

    dim3 ng((N_NODES_C + 63) / 64, 2);
    int egrid = 2048;

    // layer 1: K=35, ldW=78, edge cols at 35
    node_gemm<<<ng, 256, 0, stream>>>(x, IN_DIM_C, W1n, IN_DIM_C + EDGE_DIM_C, b1n, W1r, b1r, bufBase, bufA);
    edge_mfma<<<egrid, 256, 0, stream>>>(EAp, gnode, gvalid, ngroups, bufBase, W1n, IN_DIM_C, IN_DIM_C + EDGE_DIM_C, bufA);
    // layer 2: K=128, ldW=171, edge cols at 128
    node_gemm<<<ng, 256, 0, stream>>>(bufA, HDIM_C, W2n, HDIM_C + EDGE_DIM_C, b2n, W2r, b2r, bufBase, bufB);
    edge_mfma<<<egrid, 256, 0, stream>>>(EAp, gnode, gvalid, ngroups, bufBase, W2n, HDIM_C, HDIM_C + EDGE_DIM_C, bufB);
    // layer 3
    node_gemm<<<ng, 256, 0, stream>>>(bufB, HDIM_C, W3n, HDIM_C + EDGE_DIM_C, b3n, W3r, b3r, bufBase, bufA);
    edge_mfma<<<egrid, 256, 0, stream>>>(EAp, gnode, gvalid, ngroups, bufBase, W3n, HDIM_C, HDIM_C + EDGE_DIM_C, bufA);

    gate_kernel<<<N_NODES_C, 64, 0, stream>>>(bufA, Wg1, bg1, Wg2, bg2, Wg3, bg3, gate);
    graph_attn<<<N_GRAPHS_C, 256, 0, stream>>>(gate, grp, bufA, att, emb);
    final_mlp<<<N_GRAPHS_C, 256, 0, stream>>>(emb, u_soap, u_dimer,
                                              Wl1, bl1, Wl2, bl2, Wl3, bl3, Wl, bl, out5);
}

// Round 3
// 1859.977 us; speedup vs baseline: 1.6455x; 1.0832x over previous
//
#include <hip/hip_runtime.h>
#include <cstdint>
#include <cstddef>

#define N_NODES_C 50000
#define N_EDGES_C 1600000
#define N_GRAPHS_C 128
#define EDGE_DIM_C 43
#define IN_DIM_C 35
#define HDIM_C 128
#define MAXG_C 150000   // upper bound on #16-edge groups: N + E/16

typedef _Float16 f16x8 __attribute__((ext_vector_type(8)));
typedef float f32x4 __attribute__((ext_vector_type(4)));

__device__ __forceinline__ float fast_tanh(float x) {
    float xc = fminf(9.0f, fmaxf(-9.0f, x));
    float t = __expf(2.0f * xc);
    return (t - 1.0f) * __builtin_amdgcn_rcpf(t + 1.0f);
}

// ---------------- CSR build ----------------

__global__ __launch_bounds__(256) void hist_kernel(const int* __restrict__ src,
                                                   int* __restrict__ cnt) {
    int i = blockIdx.x * 256 + threadIdx.x;
    if (i < N_EDGES_C) atomicAdd(&cnt[src[i]], 1);
}

// dual scan: rowptr (edge CSR) and growptr (16-edge padded group index)
// 4 elements per thread per iteration.
__global__ __launch_bounds__(1024) void scan_kernel(const int* __restrict__ cnt,
                                                    int* __restrict__ rowptr,
                                                    int* __restrict__ work,
                                                    int* __restrict__ growptr,
                                                    int* __restrict__ ngroups) {
    __shared__ int wsumA[16], wsumB[16];
    __shared__ int carryA, carryB;
    int t = threadIdx.x;
    int lane = t & 63, wid = t >> 6;
    if (t == 0) { carryA = 0; carryB = 0; }
    __syncthreads();
    for (int base = 0; base < N_NODES_C; base += 4096) {
        int i0 = base + t * 4;
        int v[4], u[4];
        #pragma unroll
        for (int j = 0; j < 4; ++j) {
            int i = i0 + j;
            v[j] = (i < N_NODES_C) ? cnt[i] : 0;
            u[j] = (v[j] + 15) >> 4;
        }
        int pv[4], pu[4];
        pv[0] = 0; pu[0] = 0;
        #pragma unroll
        for (int j = 1; j < 4; ++j) { pv[j] = pv[j-1] + v[j-1]; pu[j] = pu[j-1] + u[j-1]; }
        int tA = pv[3] + v[3], tB = pu[3] + u[3];
        int x = tA, y = tB;
        #pragma unroll
        for (int off = 1; off < 64; off <<= 1) {
            int xx = __shfl_up(x, off, 64);
            int yy = __shfl_up(y, off, 64);
            if (lane >= off) { x += xx; y += yy; }
        }
        if (lane == 63) { wsumA[wid] = x; wsumB[wid] = y; }
        __syncthreads();
        if (wid == 0) {
            int wa = (lane < 16) ? wsumA[lane] : 0;
            int wb = (lane < 16) ? wsumB[lane] : 0;
            #pragma unroll
            for (int off = 1; off < 16; off <<= 1) {
                int aa = __shfl_up(wa, off, 64);
                int bb = __shfl_up(wb, off, 64);
                if (lane >= off) { wa += aa; wb += bb; }
            }
            if (lane < 16) { wsumA[lane] = wa; wsumB[lane] = wb; }
        }
        __syncthreads();
        int exA = carryA + (wid ? wsumA[wid - 1] : 0) + x - tA;
        int exB = carryB + (wid ? wsumB[wid - 1] : 0) + y - tB;
        #pragma unroll
        for (int j = 0; j < 4; ++j) {
            int i = i0 + j;
            if (i < N_NODES_C) {
                int rv = exA + pv[j];
                rowptr[i] = rv; work[i] = rv;
                growptr[i] = exB + pu[j];
            }
        }
        int totA = wsumA[15], totB = wsumB[15];
        __syncthreads();
        if (t == 0) { carryA += totA; carryB += totB; }
        __syncthreads();
    }
    if (t == 0) {
        rowptr[N_NODES_C] = carryA;
        growptr[N_NODES_C] = carryB;
        ngroups[0] = carryB;
    }
}

__global__ __launch_bounds__(256) void scatter_kernel(const int* __restrict__ src,
                                                      int* __restrict__ work,
                                                      int* __restrict__ perm) {
    int i = blockIdx.x * 256 + threadIdx.x;
    if (i < N_EDGES_C) {
        int s = src[i];
        int pos = atomicAdd(&work[s], 1);
        perm[pos] = i;
    }
}

// merged: graph bounds (binary search) + per-node meta {deg, gptr} + per-group meta {ebase, valid}
__global__ __launch_bounds__(256) void graph_misc(const int* __restrict__ rowptr,
                                                  const int* __restrict__ growptr,
                                                  const int* __restrict__ batch,
                                                  int2* __restrict__ nmeta,
                                                  int2* __restrict__ gmeta,
                                                  int* __restrict__ grp) {
    int i = blockIdx.x * 256 + threadIdx.x;
    if (i < N_NODES_C) {
        int r0 = rowptr[i], r1 = rowptr[i + 1];
        int g0 = growptr[i], g1 = growptr[i + 1];
        int deg = r1 - r0;
        nmeta[i] = make_int2(deg, g0);
        for (int g = g0; g < g1; ++g) {
            int o = (g - g0) * 16;
            int vv = deg - o; if (vv > 16) vv = 16;
            gmeta[g] = make_int2(r0 + o, vv);
        }
    }
    if (i <= N_GRAPHS_C) {
        int lo = 0, hi = N_NODES_C;
        while (lo < hi) {
            int mid = (lo + hi) >> 1;
            if (batch[mid] < i) lo = mid + 1; else hi = mid;
        }
        grp[i] = lo;
    }
}

// permute + fp32->f16 convert edge_attr into padded group layout [g][16 rows][48 k]
// grid-stride, one wave per group: lane = (row = l>>2, q = l&3), 12 cols per lane.
__global__ __launch_bounds__(256) void permute_ea(const float* __restrict__ EA,
                                                  const int* __restrict__ perm,
                                                  const int2* __restrict__ gmeta,
                                                  const int* __restrict__ ngroups_p,
                                                  _Float16* __restrict__ EAp) {
    int t = threadIdx.x;
    int lane = t & 63, wid = t >> 6;
    int row = lane >> 2, q = lane & 3;
    int ng = ngroups_p[0];
    int gstride = gridDim.x * 4;
    for (int g = blockIdx.x * 4 + wid; g < ng; g += gstride) {
        int2 gm = gmeta[g];
        int ebase = gm.x, valid = gm.y;
        bool rv = row < valid;
        int e = rv ? perm[ebase + row] : 0;
        const float* pe = EA + (size_t)e * EDGE_DIM_C;
        unsigned int pk[6];
        #pragma unroll
        for (int jj = 0; jj < 6; ++jj) {
            int c0 = q * 12 + 2 * jj;
            float v0 = (rv && c0 < EDGE_DIM_C) ? pe[c0] : 0.0f;
            float v1 = (rv && c0 + 1 < EDGE_DIM_C) ? pe[c0 + 1] : 0.0f;
            unsigned short h0 = __builtin_bit_cast(unsigned short, (_Float16)v0);
            unsigned short h1 = __builtin_bit_cast(unsigned short, (_Float16)v1);
            pk[jj] = (unsigned int)h0 | ((unsigned int)h1 << 16);
        }
        unsigned int* outp = (unsigned int*)(EAp + (size_t)g * 768 + row * 48 + q * 12);
        *(uint2*)(outp)     = make_uint2(pk[0], pk[1]);
        *(uint2*)(outp + 2) = make_uint2(pk[2], pk[3]);
        *(uint2*)(outp + 4) = make_uint2(pk[4], pk[5]);
    }
}

// ---------------- Node GEMM (Base = A@Wx.T+bn ; Root = tanh(A@Wr.T+br)) ----------------

#define BKN 32
__global__ __launch_bounds__(256) void node_gemm(
    const float* __restrict__ A, int K,
    const float* __restrict__ Wn, int ldn, const float* __restrict__ bn,
    const float* __restrict__ Wr, const float* __restrict__ br,
    float* __restrict__ Base, float* __restrict__ Root)
{
    __shared__ float At[BKN][64];
    __shared__ float Bw[BKN][128];
    int t = threadIdx.x;
    int z = blockIdx.y;
    const float* W = z ? Wr : Wn;
    int ldW = z ? K : ldn;
    const float* bias = z ? br : bn;
    float* Out = z ? Root : Base;

    int m0 = blockIdx.x * 64;
    int tn4 = (t % 32) * 4;
    int tm8 = (t / 32) * 8;
    float acc[8][4];
    #pragma unroll
    for (int a = 0; a < 8; a++)
        #pragma unroll
        for (int b = 0; b < 4; b++) acc[a][b] = 0.0f;

    int nkc = (K + BKN - 1) / BKN;
    for (int c = 0; c < nkc; c++) {
        int kc = c * BKN;
        {
            int m_l = t % 64;
            int kg = t / 64;
            int m = m0 + m_l;
            #pragma unroll
            for (int ii = 0; ii < 8; ii++) {
                int kk = kg * 8 + ii;
                int k = kc + kk;
                float v = 0.0f;
                if (m < N_NODES_C && k < K) v = A[(size_t)m * K + k];
                At[kk][m_l] = v;
            }
        }
        {
            int j = t % 128;
            int kg2 = t / 128;
            #pragma unroll
            for (int ii = 0; ii < 16; ii++) {
                int kk = kg2 * 16 + ii;
                int k = kc + kk;
                float v = 0.0f;
                if (k < K) v = W[(size_t)j * ldW + k];
                Bw[kk][j] = v;
            }
        }
        __syncthreads();
        #pragma unroll
        for (int kk = 0; kk < BKN; kk++) {
            float a[8], b[4];
            #pragma unroll
            for (int mi = 0; mi < 8; mi++) a[mi] = At[kk][tm8 + mi];
            #pragma unroll
            for (int ni = 0; ni < 4; ni++) b[ni] = Bw[kk][tn4 + ni];
            #pragma unroll
            for (int mi = 0; mi < 8; mi++)
                #pragma unroll
                for (int ni = 0; ni < 4; ni++)
                    acc[mi][ni] = fmaf(a[mi], b[ni], acc[mi][ni]);
        }
        __syncthreads();
    }

    float4 bv = *(const float4*)&bias[tn4];
    #pragma unroll
    for (int mi = 0; mi < 8; mi++) {
        int m = m0 + tm8 + mi;
        if (m < N_NODES_C) {
            float4 o;
            o.x = acc[mi][0] + bv.x;
            o.y = acc[mi][1] + bv.y;
            o.z = acc[mi][2] + bv.z;
            o.w = acc[mi][3] + bv.w;
            if (z) { o.x = fast_tanh(o.x); o.y = fast_tanh(o.y); o.z = fast_tanh(o.z); o.w = fast_tanh(o.w); }
            *(float4*)&Out[(size_t)m * HDIM_C + tn4] = o;
        }
    }
}

// ---------------- MFMA edge conv, wave-per-node ----------------
// Wave loops over the node's 16-edge groups, accumulates masked tanh sums in
// registers, shuffle-reduces once, plain store Hout = Root + sum (no atomics).
// Hout may alias Base (per-node wave ownership).

__global__ __launch_bounds__(256) void edge_mfma(
    const _Float16* __restrict__ EAp, const int2* __restrict__ nmeta,
    const float* __restrict__ Base, const float* __restrict__ Root,
    const float* __restrict__ Wfull, int colOff, int ldW,
    float* __restrict__ Hout)
{
    int t = threadIdx.x;
    int lane = t & 63, wid = t >> 6;
    int l15 = lane & 15, quad = lane >> 4;

    // B fragments: weights held in VGPRs for the whole kernel
    f16x8 bf[8][2];
    #pragma unroll
    for (int nt = 0; nt < 8; ++nt) {
        const float* wr = Wfull + (size_t)(nt * 16 + l15) * ldW + colOff;
        #pragma unroll
        for (int kt = 0; kt < 2; ++kt) {
            f16x8 b;
            #pragma unroll
            for (int j = 0; j < 8; ++j) {
                int k = kt * 32 + quad * 8 + j;
                float v = (k < EDGE_DIM_C) ? wr[k] : 0.0f;
                b[j] = (_Float16)v;
            }
            bf[nt][kt] = b;
        }
    }

    int nstride = gridDim.x * 4;
    for (int n = blockIdx.x * 4 + wid; n < N_NODES_C; n += nstride) {
        int2 nm = nmeta[n];
        int deg = nm.x, gptr = nm.y;
        const float* bp = Base + (size_t)n * HDIM_C;
        float bv[8];
        #pragma unroll
        for (int nt = 0; nt < 8; ++nt) bv[nt] = bp[nt * 16 + l15];
        float cs[8];
        #pragma unroll
        for (int nt = 0; nt < 8; ++nt) cs[nt] = 0.0f;

        int ngr = (deg + 15) >> 4;
        int rbase = quad * 4;
        for (int gi = 0; gi < ngr; ++gi) {
            int valid = deg - gi * 16; if (valid > 16) valid = 16;
            const _Float16* ap = EAp + (size_t)(gptr + gi) * 768 + l15 * 48;
            f16x8 a0 = *(const f16x8*)(ap + quad * 8);
            f16x8 a1;
            if (quad < 2) a1 = *(const f16x8*)(ap + 32 + quad * 8);
            else { f16x8 zz = {}; a1 = zz; }

            f32x4 acc[8];
            #pragma unroll
            for (int nt = 0; nt < 8; ++nt) {
                f32x4 zz = {0.f, 0.f, 0.f, 0.f};
                acc[nt] = __builtin_amdgcn_mfma_f32_16x16x32_f16(a0, bf[nt][0], zz, 0, 0, 0);
                acc[nt] = __builtin_amdgcn_mfma_f32_16x16x32_f16(a1, bf[nt][1], acc[nt], 0, 0, 0);
            }
            #pragma unroll
            for (int nt = 0; nt < 8; ++nt) {
                #pragma unroll
                for (int r = 0; r < 4; ++r) {
                    float v = fast_tanh(acc[nt][r] + bv[nt]);
                    cs[nt] += (rbase + r < valid) ? v : 0.0f;
                }
            }
        }
        #pragma unroll
        for (int nt = 0; nt < 8; ++nt) {
            cs[nt] += __shfl_xor(cs[nt], 16, 64);
            cs[nt] += __shfl_xor(cs[nt], 32, 64);
        }
        float v0, v1;
        if (quad == 0)      { v0 = cs[0]; v1 = cs[1]; }
        else if (quad == 1) { v0 = cs[2]; v1 = cs[3]; }
        else if (quad == 2) { v0 = cs[4]; v1 = cs[5]; }
        else                { v0 = cs[6]; v1 = cs[7]; }
        int c0 = quad * 32 + l15;
        size_t rowb = (size_t)n * HDIM_C;
        Hout[rowb + c0]      = Root[rowb + c0] + v0;
        Hout[rowb + c0 + 16] = Root[rowb + c0 + 16] + v1;
    }
}

// ---------------- Gate MLP as tiled GEMM: 64 nodes/block, 128->64->32->1 ----------------

__global__ __launch_bounds__(256) void gate_kernel(
    const float* __restrict__ h,
    const float* __restrict__ Wg1, const float* __restrict__ bg1,
    const float* __restrict__ Wg2, const float* __restrict__ bg2,
    const float* __restrict__ Wg3, const float* __restrict__ bg3,
    float* __restrict__ gate)
{
    __shared__ float Ht[128][65];
    __shared__ float G1[64][65];
    __shared__ float G2[32][65];
    int t = threadIdx.x;
    int m0 = blockIdx.x * 64;
    // stage h tile (transposed)
    #pragma unroll
    for (int ii = 0; ii < 32; ++ii) {
        int flat = ii * 256 + t;
        int k = flat & 127, m = flat >> 7;
        float v = (m0 + m < N_NODES_C) ? h[(size_t)(m0 + m) * HDIM_C + k] : 0.0f;
        Ht[k][m] = v;
    }
    __syncthreads();
    int m = t & 63, slab = t >> 6;
    // layer1: 64 outs, 16 per thread-slab
    {
        float a[16];
        #pragma unroll
        for (int jj = 0; jj < 16; ++jj) a[jj] = bg1[slab * 16 + jj];
        for (int k = 0; k < 128; ++k) {
            float hv = Ht[k][m];
            #pragma unroll
            for (int jj = 0; jj < 16; ++jj)
                a[jj] = fmaf(Wg1[(size_t)(slab * 16 + jj) * 128 + k], hv, a[jj]);
        }
        #pragma unroll
        for (int jj = 0; jj < 16; ++jj) G1[slab * 16 + jj][m] = fmaxf(a[jj], 0.0f);
    }
    __syncthreads();
    // layer2: 32 outs, 8 per slab
    {
        float b[8];
        #pragma unroll
        for (int jj = 0; jj < 8; ++jj) b[jj] = bg2[slab * 8 + jj];
        for (int k = 0; k < 64; ++k) {
            float gv = G1[k][m];
            #pragma unroll
            for (int jj = 0; jj < 8; ++jj)
                b[jj] = fmaf(Wg2[(size_t)(slab * 8 + jj) * 64 + k], gv, b[jj]);
        }
        #pragma unroll
        for (int jj = 0; jj < 8; ++jj) G2[slab * 8 + jj][m] = fmaxf(b[jj], 0.0f);
    }
    __syncthreads();
    // layer3
    if (t < 64 && m0 + t < N_NODES_C) {
        float s = bg3[0];
        #pragma unroll
        for (int k = 0; k < 32; ++k) s = fmaf(Wg3[k], G2[k][t], s);
        gate[m0 + t] = s;
    }
}

// ---------------- Per-graph softmax + attention + embedding ----------------

__global__ __launch_bounds__(256) void graph_attn(
    const float* __restrict__ gate, const int* __restrict__ grp,
    const float* __restrict__ h3, float* __restrict__ att_out,
    float* __restrict__ emb)
{
    int g = blockIdx.x;
    int t = threadIdx.x;
    int s = grp[g], e = grp[g + 1];
    __shared__ float red[256];
    __shared__ float attb[256];

    float m = -3.4e38f;
    for (int i = s + t; i < e; i += 256) m = fmaxf(m, gate[i]);
    red[t] = m;
    __syncthreads();
    #pragma unroll
    for (int off = 128; off >= 1; off >>= 1) {
        if (t < off) red[t] = fmaxf(red[t], red[t + off]);
        __syncthreads();
    }
    m = red[0];
    __syncthreads();

    float sum = 0.0f;
    for (int i = s + t; i < e; i += 256) sum += __expf(gate[i] - m);
    red[t] = sum;
    __syncthreads();
    #pragma unroll
    for (int off = 128; off >= 1; off >>= 1) {
        if (t < off) red[t] += red[t + off];
        __syncthreads();
    }
    float scale = 1.0f / (red[0] + 1e-16f);
    __syncthreads();

    int j = t & 127;
    int half = t >> 7;
    float acc = 0.0f;
    for (int base = s; base < e; base += 256) {
        int i = base + t;
        float a = 0.0f;
        if (i < e) {
            a = __expf(gate[i] - m) * scale;
            att_out[i] = a;
        }
        attb[t] = a;
        __syncthreads();
        int cnt = e - base; if (cnt > 256) cnt = 256;
        for (int r = half; r < cnt; r += 2)
            acc = fmaf(attb[r], h3[(size_t)(base + r) * HDIM_C + j], acc);
        __syncthreads();
    }
    red[t] = acc;
    __syncthreads();
    if (t < 128) emb[(size_t)g * 128 + t] = red[t] + red[t + 128];
}

// ---------------- Final MLP ----------------

__global__ __launch_bounds__(256) void final_mlp(
    const float* __restrict__ emb, const float* __restrict__ us, const float* __restrict__ ud,
    const float* __restrict__ Wl1, const float* __restrict__ bl1,
    const float* __restrict__ Wl2, const float* __restrict__ bl2,
    const float* __restrict__ Wl3, const float* __restrict__ bl3,
    const float* __restrict__ Wl, const float* __restrict__ bl,
    float* __restrict__ out5)
{
    int g = blockIdx.x;
    int t = threadIdx.x;
    __shared__ float e2[256], o1[256], o2[128], o3[64], o4[4];
    if (t < 128) e2[t] = emb[(size_t)g * 128 + t];
    else if (t < 192) e2[t] = us[(size_t)g * 64 + (t - 128)];
    else e2[t] = ud[(size_t)g * 64 + (t - 192)];
    __syncthreads();
    {
        float s = bl1[t];
        const float* wr = Wl1 + (size_t)t * 256;
        #pragma unroll 8
        for (int k = 0; k < 256; k++) s = fmaf(wr[k], e2[k], s);
        o1[t] = fmaxf(s, 0.0f);
    }
    __syncthreads();
    if (t < 128) {
        float s = bl2[t];
        const float* wr = Wl2 + (size_t)t * 256;
        #pragma unroll 8
        for (int k = 0; k < 256; k++) s = fmaf(wr[k], o1[k], s);
        o2[t] = fmaxf(s, 0.0f);
    }
    __syncthreads();
    if (t < 64) {
        float s = bl3[t];
        const float* wr = Wl3 + (size_t)t * 128;
        #pragma unroll 8
        for (int k = 0; k < 128; k++) s = fmaf(wr[k], o2[k], s);
        o3[t] = fmaxf(s, 0.0f);
    }
    __syncthreads();
    if (t < 4) {
        float s = bl[t];
        const float* wr = Wl + (size_t)t * 64;
        #pragma unroll 8
        for (int k = 0; k < 64; k++) s = fmaf(wr[k], o3[k], s);
        o4[t] = s;
    }
    __syncthreads();
    if (t < 5) {
        float v = (t < 4) ? o4[t] : (o4[0] + o4[1] + o4[2] + o4[3]);
        out5[(size_t)g * 5 + t] = v;
    }
}

// ---------------- launch ----------------

extern "C" void kernel_launch(void* const* d_in, const int* in_sizes, int n_in,
                              void* d_out, int out_size, void* d_ws, size_t ws_size,
                              hipStream_t stream) {
    const float* x       = (const float*)d_in[0];
    const float* ea      = (const float*)d_in[1];
    const float* u_soap  = (const float*)d_in[2];
    const float* u_dimer = (const float*)d_in[3];
    const float* W1n = (const float*)d_in[4];   const float* b1n = (const float*)d_in[5];
    const float* W1r = (const float*)d_in[6];   const float* b1r = (const float*)d_in[7];
    const float* W2n = (const float*)d_in[8];   const float* b2n = (const float*)d_in[9];
    const float* W2r = (const float*)d_in[10];  const float* b2r = (const float*)d_in[11];
    const float* W3n = (const float*)d_in[12];  const float* b3n = (const float*)d_in[13];
    const float* W3r = (const float*)d_in[14];  const float* b3r = (const float*)d_in[15];
    const float* Wg1 = (const float*)d_in[16];  const float* bg1 = (const float*)d_in[17];
    const float* Wg2 = (const float*)d_in[18];  const float* bg2 = (const float*)d_in[19];
    const float* Wg3 = (const float*)d_in[20];  const float* bg3 = (const float*)d_in[21];
    const float* Wl1 = (const float*)d_in[22];  const float* bl1 = (const float*)d_in[23];
    const float* Wl2 = (const float*)d_in[24];  const float* bl2 = (const float*)d_in[25];
    const float* Wl3 = (const float*)d_in[26];  const float* bl3 = (const float*)d_in[27];
    const float* Wl  = (const float*)d_in[28];  const float* bl  = (const float*)d_in[29];
    const int* eidx  = (const int*)d_in[30];
    const int* batch = (const int*)d_in[31];
    const int* src = eidx;  // row 0 of edge_index

    float* out5 = (float*)d_out;
    float* att  = out5 + (size_t)N_GRAPHS_C * 5;

    char* p = (char*)d_ws;
    size_t off = 0;
    auto alloc = [&](size_t bytes) -> void* {
        void* r = p + off;
        off += (bytes + 255) & ~(size_t)255;
        return r;
    };
    int* cnt     = (int*)alloc((size_t)N_NODES_C * 4);
    int* rowptr  = (int*)alloc((size_t)(N_NODES_C + 1) * 4);
    int* growptr = (int*)alloc((size_t)(N_NODES_C + 1) * 4);
    int* work    = (int*)alloc((size_t)N_NODES_C * 4);
    int* perm    = (int*)alloc((size_t)N_EDGES_C * 4);
    int* grp     = (int*)alloc((size_t)(N_GRAPHS_C + 1) * 4);
    int* ngroups = (int*)alloc(256);
    int2* nmeta  = (int2*)alloc((size_t)N_NODES_C * 8);
    int2* gmeta  = (int2*)alloc((size_t)MAXG_C * 8);
    float* gate  = (float*)alloc((size_t)N_NODES_C * 4);
    float* emb   = (float*)alloc((size_t)N_GRAPHS_C * 128 * 4);
    float* bufP  = (float*)alloc((size_t)N_NODES_C * HDIM_C * 4);
    float* bufQ  = (float*)alloc((size_t)N_NODES_C * HDIM_C * 4);
    float* bufR  = (float*)alloc((size_t)N_NODES_C * HDIM_C * 4);
    _Float16* EAp = (_Float16*)alloc((size_t)MAXG_C * 768 * 2);

    hipMemsetAsync(cnt, 0, (size_t)N_NODES_C * 4, stream);

    int eblocks = (N_EDGES_C + 255) / 256;
    hist_kernel<<<eblocks, 256, 0, stream>>>(src, cnt);
    scan_kernel<<<1, 1024, 0, stream>>>(cnt, rowptr, work, growptr, ngroups);
    scatter_kernel<<<eblocks, 256, 0, stream>>>(src, work, perm);
    graph_misc<<<(N_NODES_C + 255) / 256, 256, 0, stream>>>(rowptr, growptr, batch, nmeta, gmeta, grp);
    permute_ea<<<1536, 256, 0, stream>>>(ea, perm, gmeta, ngroups, EAp);

    dim3 ng((N_NODES_C + 63) / 64, 2);
    int egrid = 2048;

    // L1: x -> (Base=P, Root=Q); edge writes h1 into P
    node_gemm<<<ng, 256, 0, stream>>>(x, IN_DIM_C, W1n, IN_DIM_C + EDGE_DIM_C, b1n, W1r, b1r, bufP, bufQ);
    edge_mfma<<<egrid, 256, 0, stream>>>(EAp, nmeta, bufP, bufQ, W1n, IN_DIM_C, IN_DIM_C + EDGE_DIM_C, bufP);
    // L2: P -> (Base=Q, Root=R); edge writes h2 into Q
    node_gemm<<<ng, 256, 0, stream>>>(bufP, HDIM_C, W2n, HDIM_C + EDGE_DIM_C, b2n, W2r, b2r, bufQ, bufR);
    edge_mfma<<<egrid, 256, 0, stream>>>(EAp, nmeta, bufQ, bufR, W2n, HDIM_C, HDIM_C + EDGE_DIM_C, bufQ);
    // L3: Q -> (Base=P, Root=R); edge writes h3 into P
    node_gemm<<<ng, 256, 0, stream>>>(bufQ, HDIM_C, W3n, HDIM_C + EDGE_DIM_C, b3n, W3r, b3r, bufP, bufR);
    edge_mfma<<<egrid, 256, 0, stream>>>(EAp, nmeta, bufP, bufR, W3n, HDIM_C, HDIM_C + EDGE_DIM_C, bufP);

    gate_kernel<<<(N_NODES_C + 63) / 64, 256, 0, stream>>>(bufP, Wg1, bg1, Wg2, bg2, Wg3, bg3, gate);
    graph_attn<<<N_GRAPHS_C, 256, 0, stream>>>(gate, grp, bufP, att, emb);
    final_mlp<<<N_GRAPHS_C, 256, 0, stream>>>(emb, u_soap, u_dimer,
                                              Wl1, bl1, Wl2, bl2, Wl3, bl3, Wl, bl, out5);
}

// Round 4
// 1712.215 us; speedup vs baseline: 1.7875x; 1.0863x over previous
//
#include <hip/hip_runtime.h>
#include <cstdint>
#include <cstddef>

#define N_NODES_C 50000
#define N_EDGES_C 1600000
#define N_GRAPHS_C 128
#define EDGE_DIM_C 43
#define IN_DIM_C 35
#define HDIM_C 128
#define MAXG_C 150000   // upper bound on #16-edge groups: N + E/16

typedef _Float16 f16x8 __attribute__((ext_vector_type(8)));
typedef float f32x4 __attribute__((ext_vector_type(4)));

__device__ __forceinline__ float fast_tanh(float x) {
    float xc = fminf(9.0f, fmaxf(-9.0f, x));
    float t = __expf(2.0f * xc);
    return (t - 1.0f) * __builtin_amdgcn_rcpf(t + 1.0f);
}

// ---------------- CSR build ----------------

__global__ __launch_bounds__(256) void hist_kernel(const int* __restrict__ src,
                                                   int* __restrict__ cnt) {
    int i = blockIdx.x * 256 + threadIdx.x;
    if (i < N_EDGES_C) atomicAdd(&cnt[src[i]], 1);
}

// dual scan: rowptr (edge CSR) and growptr (16-edge padded group index)
__global__ __launch_bounds__(1024) void scan_kernel(const int* __restrict__ cnt,
                                                    int* __restrict__ rowptr,
                                                    int* __restrict__ work,
                                                    int* __restrict__ growptr,
                                                    int* __restrict__ ngroups) {
    __shared__ int wsumA[16], wsumB[16];
    __shared__ int carryA, carryB;
    int t = threadIdx.x;
    int lane = t & 63, wid = t >> 6;
    if (t == 0) { carryA = 0; carryB = 0; }
    __syncthreads();
    for (int base = 0; base < N_NODES_C; base += 4096) {
        int i0 = base + t * 4;
        int v[4], u[4];
        #pragma unroll
        for (int j = 0; j < 4; ++j) {
            int i = i0 + j;
            v[j] = (i < N_NODES_C) ? cnt[i] : 0;
            u[j] = (v[j] + 15) >> 4;
        }
        int pv[4], pu[4];
        pv[0] = 0; pu[0] = 0;
        #pragma unroll
        for (int j = 1; j < 4; ++j) { pv[j] = pv[j-1] + v[j-1]; pu[j] = pu[j-1] + u[j-1]; }
        int tA = pv[3] + v[3], tB = pu[3] + u[3];
        int x = tA, y = tB;
        #pragma unroll
        for (int off = 1; off < 64; off <<= 1) {
            int xx = __shfl_up(x, off, 64);
            int yy = __shfl_up(y, off, 64);
            if (lane >= off) { x += xx; y += yy; }
        }
        if (lane == 63) { wsumA[wid] = x; wsumB[wid] = y; }
        __syncthreads();
        if (wid == 0) {
            int wa = (lane < 16) ? wsumA[lane] : 0;
            int wb = (lane < 16) ? wsumB[lane] : 0;
            #pragma unroll
            for (int off = 1; off < 16; off <<= 1) {
                int aa = __shfl_up(wa, off, 64);
                int bb = __shfl_up(wb, off, 64);
                if (lane >= off) { wa += aa; wb += bb; }
            }
            if (lane < 16) { wsumA[lane] = wa; wsumB[lane] = wb; }
        }
        __syncthreads();
        int exA = carryA + (wid ? wsumA[wid - 1] : 0) + x - tA;
        int exB = carryB + (wid ? wsumB[wid - 1] : 0) + y - tB;
        #pragma unroll
        for (int j = 0; j < 4; ++j) {
            int i = i0 + j;
            if (i < N_NODES_C) {
                int rv = exA + pv[j];
                rowptr[i] = rv; work[i] = rv;
                growptr[i] = exB + pu[j];
            }
        }
        int totA = wsumA[15], totB = wsumB[15];
        __syncthreads();
        if (t == 0) { carryA += totA; carryB += totB; }
        __syncthreads();
    }
    if (t == 0) {
        rowptr[N_NODES_C] = carryA;
        growptr[N_NODES_C] = carryB;
        ngroups[0] = carryB;
    }
}

// records each edge's position within its node's CSR segment
__global__ __launch_bounds__(256) void scatter_kernel(const int* __restrict__ src,
                                                      int* __restrict__ work,
                                                      int* __restrict__ epos) {
    int i = blockIdx.x * 256 + threadIdx.x;
    if (i < N_EDGES_C) {
        int s = src[i];
        int pos = atomicAdd(&work[s], 1);
        epos[i] = pos;
    }
}

// merged: graph bounds (binary search) + per-node meta {deg, gptr}
__global__ __launch_bounds__(256) void graph_misc(const int* __restrict__ rowptr,
                                                  const int* __restrict__ growptr,
                                                  const int* __restrict__ batch,
                                                  int2* __restrict__ nmeta,
                                                  int* __restrict__ grp) {
    int i = blockIdx.x * 256 + threadIdx.x;
    if (i < N_NODES_C) {
        int deg = rowptr[i + 1] - rowptr[i];
        nmeta[i] = make_int2(deg, growptr[i]);
    }
    if (i <= N_GRAPHS_C) {
        int lo = 0, hi = N_NODES_C;
        while (lo < hi) {
            int mid = (lo + hi) >> 1;
            if (batch[mid] < i) lo = mid + 1; else hi = mid;
        }
        grp[i] = lo;
    }
}

// zero the padding rows of each node's last (partial) group
__global__ __launch_bounds__(256) void pad_zero(const int2* __restrict__ nmeta,
                                                _Float16* __restrict__ EAp) {
    int id = blockIdx.x * 256 + threadIdx.x;
    int n = id >> 4, row = id & 15;
    if (n >= N_NODES_C) return;
    int2 nm = nmeta[n];
    int deg = nm.x;
    if (deg == 0) return;
    int rem = deg & 15;
    if (rem == 0 || row < rem) return;
    int g = nm.y + ((deg + 15) >> 4) - 1;
    uint2* dst = (uint2*)(EAp + (size_t)g * 768 + row * 48);
    uint2 z = make_uint2(0u, 0u);
    #pragma unroll
    for (int j = 0; j < 12; ++j) dst[j] = z;
}

// STREAMING permute: read EA in edge order (coalesced), compute padded slot,
// scatter-write packed f16 rows. 4 lanes per edge, 12 cols each.
__global__ __launch_bounds__(256) void permute_ea(const float* __restrict__ EA,
                                                  const int* __restrict__ src,
                                                  const int* __restrict__ epos,
                                                  const int* __restrict__ rowptr,
                                                  const int* __restrict__ growptr,
                                                  _Float16* __restrict__ EAp) {
    int t = threadIdx.x;
    int e = blockIdx.x * 64 + (t >> 2);
    int q = t & 3;
    if (e >= N_EDGES_C) return;
    int node = src[e];
    int pos = epos[e];
    int r = pos - rowptr[node];          // position within node's list
    int g = growptr[node] + (r >> 4);    // group
    int row = r & 15;

    const float* pe = EA + (size_t)e * EDGE_DIM_C;
    unsigned int pk[6];
    #pragma unroll
    for (int jj = 0; jj < 6; ++jj) {
        int c0 = q * 12 + 2 * jj;
        float v0 = (c0 < EDGE_DIM_C) ? pe[c0] : 0.0f;
        float v1 = (c0 + 1 < EDGE_DIM_C) ? pe[c0 + 1] : 0.0f;
        unsigned short h0 = __builtin_bit_cast(unsigned short, (_Float16)v0);
        unsigned short h1 = __builtin_bit_cast(unsigned short, (_Float16)v1);
        pk[jj] = (unsigned int)h0 | ((unsigned int)h1 << 16);
    }
    unsigned int* outp = (unsigned int*)(EAp + (size_t)g * 768 + row * 48 + q * 12);
    *(uint2*)(outp)     = make_uint2(pk[0], pk[1]);
    *(uint2*)(outp + 2) = make_uint2(pk[2], pk[3]);
    *(uint2*)(outp + 4) = make_uint2(pk[4], pk[5]);
}

// ---------------- Node GEMM (Base = A@Wx.T+bn ; Root = tanh(A@Wr.T+br)) ----------------

#define BKN 32
__global__ __launch_bounds__(256) void node_gemm(
    const float* __restrict__ A, int K,
    const float* __restrict__ Wn, int ldn, const float* __restrict__ bn,
    const float* __restrict__ Wr, const float* __restrict__ br,
    float* __restrict__ Base, float* __restrict__ Root)
{
    __shared__ float At[BKN][64];
    __shared__ float Bw[BKN][128];
    int t = threadIdx.x;
    int z = blockIdx.y;
    const float* W = z ? Wr : Wn;
    int ldW = z ? K : ldn;
    const float* bias = z ? br : bn;
    float* Out = z ? Root : Base;

    int m0 = blockIdx.x * 64;
    int tn4 = (t % 32) * 4;
    int tm8 = (t / 32) * 8;
    float acc[8][4];
    #pragma unroll
    for (int a = 0; a < 8; a++)
        #pragma unroll
        for (int b = 0; b < 4; b++) acc[a][b] = 0.0f;

    int nkc = (K + BKN - 1) / BKN;
    for (int c = 0; c < nkc; c++) {
        int kc = c * BKN;
        // A tile, coalesced: thread = (row m_l = t/4, quarter q = t%4), 8 contiguous floats
        {
            int m_l = t >> 2;
            int q = t & 3;
            int m = m0 + m_l;
            #pragma unroll
            for (int ii = 0; ii < 8; ii++) {
                int kk = q * 8 + ii;
                int k = kc + kk;
                float v = 0.0f;
                if (m < N_NODES_C && k < K) v = A[(size_t)m * K + k];
                At[kk][m_l] = v;
            }
        }
        {
            int j = t % 128;
            int kg2 = t / 128;
            #pragma unroll
            for (int ii = 0; ii < 16; ii++) {
                int kk = kg2 * 16 + ii;
                int k = kc + kk;
                float v = 0.0f;
                if (k < K) v = W[(size_t)j * ldW + k];
                Bw[kk][j] = v;
            }
        }
        __syncthreads();
        #pragma unroll
        for (int kk = 0; kk < BKN; kk++) {
            float a[8], b[4];
            #pragma unroll
            for (int mi = 0; mi < 8; mi++) a[mi] = At[kk][tm8 + mi];
            #pragma unroll
            for (int ni = 0; ni < 4; ni++) b[ni] = Bw[kk][tn4 + ni];
            #pragma unroll
            for (int mi = 0; mi < 8; mi++)
                #pragma unroll
                for (int ni = 0; ni < 4; ni++)
                    acc[mi][ni] = fmaf(a[mi], b[ni], acc[mi][ni]);
        }
        __syncthreads();
    }

    float4 bv = *(const float4*)&bias[tn4];
    #pragma unroll
    for (int mi = 0; mi < 8; mi++) {
        int m = m0 + tm8 + mi;
        if (m < N_NODES_C) {
            float4 o;
            o.x = acc[mi][0] + bv.x;
            o.y = acc[mi][1] + bv.y;
            o.z = acc[mi][2] + bv.z;
            o.w = acc[mi][3] + bv.w;
            if (z) { o.x = fast_tanh(o.x); o.y = fast_tanh(o.y); o.z = fast_tanh(o.z); o.w = fast_tanh(o.w); }
            *(float4*)&Out[(size_t)m * HDIM_C + tn4] = o;
        }
    }
}

// ---------------- MFMA edge conv, wave-per-node, pipelined group loop ----------------

__global__ __launch_bounds__(256) void edge_mfma(
    const _Float16* __restrict__ EAp, const int2* __restrict__ nmeta,
    const float* __restrict__ Base, const float* __restrict__ Root,
    const float* __restrict__ Wfull, int colOff, int ldW,
    float* __restrict__ Hout)
{
    int t = threadIdx.x;
    int lane = t & 63, wid = t >> 6;
    int l15 = lane & 15, quad = lane >> 4;

    // B fragments: weights held in VGPRs for the whole kernel
    f16x8 bf[8][2];
    #pragma unroll
    for (int nt = 0; nt < 8; ++nt) {
        const float* wr = Wfull + (size_t)(nt * 16 + l15) * ldW + colOff;
        #pragma unroll
        for (int kt = 0; kt < 2; ++kt) {
            f16x8 b;
            #pragma unroll
            for (int j = 0; j < 8; ++j) {
                int k = kt * 32 + quad * 8 + j;
                float v = (k < EDGE_DIM_C) ? wr[k] : 0.0f;
                b[j] = (_Float16)v;
            }
            bf[nt][kt] = b;
        }
    }

    int aoff0 = l15 * 48 + quad * 8;
    int aoff1 = l15 * 48 + 32 + ((quad & 1) * 8);  // only quads 0,1 use real a1
    bool useA1 = (quad < 2);

    int nstride = gridDim.x * 4;
    for (int n = blockIdx.x * 4 + wid; n < N_NODES_C; n += nstride) {
        int2 nm = nmeta[n];
        int deg = nm.x, gptr = nm.y;
        const float* bp = Base + (size_t)n * HDIM_C;
        float bv[8];
        #pragma unroll
        for (int nt = 0; nt < 8; ++nt) bv[nt] = bp[nt * 16 + l15];
        float cs[8];
        #pragma unroll
        for (int nt = 0; nt < 8; ++nt) cs[nt] = 0.0f;

        int ngr = (deg + 15) >> 4;
        int rbase = quad * 4;
        if (ngr > 0) {
            const _Float16* apb = EAp + (size_t)gptr * 768;
            f16x8 zz8 = {};
            f16x8 a0 = *(const f16x8*)(apb + aoff0);
            f16x8 a1 = useA1 ? *(const f16x8*)(apb + aoff1) : zz8;
            for (int gi = 0; gi < ngr; ++gi) {
                // prefetch next group's fragments before consuming current
                f16x8 n0 = a0, n1 = a1;
                if (gi + 1 < ngr) {
                    const _Float16* apn = apb + (size_t)(gi + 1) * 768;
                    n0 = *(const f16x8*)(apn + aoff0);
                    n1 = useA1 ? *(const f16x8*)(apn + aoff1) : zz8;
                }
                int valid = deg - gi * 16; if (valid > 16) valid = 16;
                f32x4 acc[8];
                #pragma unroll
                for (int nt = 0; nt < 8; ++nt) {
                    f32x4 zz = {0.f, 0.f, 0.f, 0.f};
                    acc[nt] = __builtin_amdgcn_mfma_f32_16x16x32_f16(a0, bf[nt][0], zz, 0, 0, 0);
                    acc[nt] = __builtin_amdgcn_mfma_f32_16x16x32_f16(a1, bf[nt][1], acc[nt], 0, 0, 0);
                }
                #pragma unroll
                for (int nt = 0; nt < 8; ++nt) {
                    #pragma unroll
                    for (int r = 0; r < 4; ++r) {
                        float v = fast_tanh(acc[nt][r] + bv[nt]);
                        cs[nt] += (rbase + r < valid) ? v : 0.0f;
                    }
                }
                a0 = n0; a1 = n1;
            }
        }
        #pragma unroll
        for (int nt = 0; nt < 8; ++nt) {
            cs[nt] += __shfl_xor(cs[nt], 16, 64);
            cs[nt] += __shfl_xor(cs[nt], 32, 64);
        }
        float v0, v1;
        if (quad == 0)      { v0 = cs[0]; v1 = cs[1]; }
        else if (quad == 1) { v0 = cs[2]; v1 = cs[3]; }
        else if (quad == 2) { v0 = cs[4]; v1 = cs[5]; }
        else                { v0 = cs[6]; v1 = cs[7]; }
        int c0 = quad * 32 + l15;
        size_t rowb = (size_t)n * HDIM_C;
        Hout[rowb + c0]      = Root[rowb + c0] + v0;
        Hout[rowb + c0 + 16] = Root[rowb + c0 + 16] + v1;
    }
}

// ---------------- Gate MLP as tiled GEMM: 64 nodes/block, 128->64->32->1 ----------------

__global__ __launch_bounds__(256) void gate_kernel(
    const float* __restrict__ h,
    const float* __restrict__ Wg1, const float* __restrict__ bg1,
    const float* __restrict__ Wg2, const float* __restrict__ bg2,
    const float* __restrict__ Wg3, const float* __restrict__ bg3,
    float* __restrict__ gate)
{
    __shared__ float Ht[128][65];
    __shared__ float G1[64][65];
    __shared__ float G2[32][65];
    int t = threadIdx.x;
    int m0 = blockIdx.x * 64;
    #pragma unroll
    for (int ii = 0; ii < 32; ++ii) {
        int flat = ii * 256 + t;
        int k = flat & 127, m = flat >> 7;
        float v = (m0 + m < N_NODES_C) ? h[(size_t)(m0 + m) * HDIM_C + k] : 0.0f;
        Ht[k][m] = v;
    }
    __syncthreads();
    int m = t & 63, slab = t >> 6;
    {
        float a[16];
        #pragma unroll
        for (int jj = 0; jj < 16; ++jj) a[jj] = bg1[slab * 16 + jj];
        for (int k = 0; k < 128; ++k) {
            float hv = Ht[k][m];
            #pragma unroll
            for (int jj = 0; jj < 16; ++jj)
                a[jj] = fmaf(Wg1[(size_t)(slab * 16 + jj) * 128 + k], hv, a[jj]);
        }
        #pragma unroll
        for (int jj = 0; jj < 16; ++jj) G1[slab * 16 + jj][m] = fmaxf(a[jj], 0.0f);
    }
    __syncthreads();
    {
        float b[8];
        #pragma unroll
        for (int jj = 0; jj < 8; ++jj) b[jj] = bg2[slab * 8 + jj];
        for (int k = 0; k < 64; ++k) {
            float gv = G1[k][m];
            #pragma unroll
            for (int jj = 0; jj < 8; ++jj)
                b[jj] = fmaf(Wg2[(size_t)(slab * 8 + jj) * 64 + k], gv, b[jj]);
        }
        #pragma unroll
        for (int jj = 0; jj < 8; ++jj) G2[slab * 8 + jj][m] = fmaxf(b[jj], 0.0f);
    }
    __syncthreads();
    if (t < 64 && m0 + t < N_NODES_C) {
        float s = bg3[0];
        #pragma unroll
        for (int k = 0; k < 32; ++k) s = fmaf(Wg3[k], G2[k][t], s);
        gate[m0 + t] = s;
    }
}

// ---------------- Per-graph softmax + attention + embedding ----------------

__global__ __launch_bounds__(256) void graph_attn(
    const float* __restrict__ gate, const int* __restrict__ grp,
    const float* __restrict__ h3, float* __restrict__ att_out,
    float* __restrict__ emb)
{
    int g = blockIdx.x;
    int t = threadIdx.x;
    int s = grp[g], e = grp[g + 1];
    __shared__ float red[256];
    __shared__ float attb[256];

    float m = -3.4e38f;
    for (int i = s + t; i < e; i += 256) m = fmaxf(m, gate[i]);
    red[t] = m;
    __syncthreads();
    #pragma unroll
    for (int off = 128; off >= 1; off >>= 1) {
        if (t < off) red[t] = fmaxf(red[t], red[t + off]);
        __syncthreads();
    }
    m = red[0];
    __syncthreads();

    float sum = 0.0f;
    for (int i = s + t; i < e; i += 256) sum += __expf(gate[i] - m);
    red[t] = sum;
    __syncthreads();
    #pragma unroll
    for (int off = 128; off >= 1; off >>= 1) {
        if (t < off) red[t] += red[t + off];
        __syncthreads();
    }
    float scale = 1.0f / (red[0] + 1e-16f);
    __syncthreads();

    int j = t & 127;
    int half = t >> 7;
    float acc = 0.0f;
    for (int base = s; base < e; base += 256) {
        int i = base + t;
        float a = 0.0f;
        if (i < e) {
            a = __expf(gate[i] - m) * scale;
            att_out[i] = a;
        }
        attb[t] = a;
        __syncthreads();
        int cnt = e - base; if (cnt > 256) cnt = 256;
        for (int r = half; r < cnt; r += 2)
            acc = fmaf(attb[r], h3[(size_t)(base + r) * HDIM_C + j], acc);
        __syncthreads();
    }
    red[t] = acc;
    __syncthreads();
    if (t < 128) emb[(size_t)g * 128 + t] = red[t] + red[t + 128];
}

// ---------------- Final MLP ----------------

__global__ __launch_bounds__(256) void final_mlp(
    const float* __restrict__ emb, const float* __restrict__ us, const float* __restrict__ ud,
    const float* __restrict__ Wl1, const float* __restrict__ bl1,
    const float* __restrict__ Wl2, const float* __restrict__ bl2,
    const float* __restrict__ Wl3, const float* __restrict__ bl3,
    const float* __restrict__ Wl, const float* __restrict__ bl,
    float* __restrict__ out5)
{
    int g = blockIdx.x;
    int t = threadIdx.x;
    __shared__ float e2[256], o1[256], o2[128], o3[64], o4[4];
    if (t < 128) e2[t] = emb[(size_t)g * 128 + t];
    else if (t < 192) e2[t] = us[(size_t)g * 64 + (t - 128)];
    else e2[t] = ud[(size_t)g * 64 + (t - 192)];
    __syncthreads();
    {
        float s = bl1[t];
        const float* wr = Wl1 + (size_t)t * 256;
        #pragma unroll 8
        for (int k = 0; k < 256; k++) s = fmaf(wr[k], e2[k], s);
        o1[t] = fmaxf(s, 0.0f);
    }
    __syncthreads();
    if (t < 128) {
        float s = bl2[t];
        const float* wr = Wl2 + (size_t)t * 256;
        #pragma unroll 8
        for (int k = 0; k < 256; k++) s = fmaf(wr[k], o1[k], s);
        o2[t] = fmaxf(s, 0.0f);
    }
    __syncthreads();
    if (t < 64) {
        float s = bl3[t];
        const float* wr = Wl3 + (size_t)t * 128;
        #pragma unroll 8
        for (int k = 0; k < 128; k++) s = fmaf(wr[k], o2[k], s);
        o3[t] = fmaxf(s, 0.0f);
    }
    __syncthreads();
    if (t < 4) {
        float s = bl[t];
        const float* wr = Wl + (size_t)t * 64;
        #pragma unroll 8
        for (int k = 0; k < 64; k++) s = fmaf(wr[k], o3[k], s);
        o4[t] = s;
    }
    __syncthreads();
    if (t < 5) {
        float v = (t < 4) ? o4[t] : (o4[0] + o4[1] + o4[2] + o4[3]);
        out5[(size_t)g * 5 + t] = v;
    }
}

// ---------------- launch ----------------

extern "C" void kernel_launch(void* const* d_in, const int* in_sizes, int n_in,
                              void* d_out, int out_size, void* d_ws, size_t ws_size,
                              hipStream_t stream) {
    const float* x       = (const float*)d_in[0];
    const float* ea      = (const float*)d_in[1];
    const float* u_soap  = (const float*)d_in[2];
    const float* u_dimer = (const float*)d_in[3];
    const float* W1n = (const float*)d_in[4];   const float* b1n = (const float*)d_in[5];
    const float* W1r = (const float*)d_in[6];   const float* b1r = (const float*)d_in[7];
    const float* W2n = (const float*)d_in[8];   const float* b2n = (const float*)d_in[9];
    const float* W2r = (const float*)d_in[10];  const float* b2r = (const float*)d_in[11];
    const float* W3n = (const float*)d_in[12];  const float* b3n = (const float*)d_in[13];
    const float* W3r = (const float*)d_in[14];  const float* b3r = (const float*)d_in[15];
    const float* Wg1 = (const float*)d_in[16];  const float* bg1 = (const float*)d_in[17];
    const float* Wg2 = (const float*)d_in[18];  const float* bg2 = (const float*)d_in[19];
    const float* Wg3 = (const float*)d_in[20];  const float* bg3 = (const float*)d_in[21];
    const float* Wl1 = (const float*)d_in[22];  const float* bl1 = (const float*)d_in[23];
    const float* Wl2 = (const float*)d_in[24];  const float* bl2 = (const float*)d_in[25];
    const float* Wl3 = (const float*)d_in[26];  const float* bl3 = (const float*)d_in[27];
    const float* Wl  = (const float*)d_in[28];  const float* bl  = (const float*)d_in[29];
    const int* eidx  = (const int*)d_in[30];
    const int* batch = (const int*)d_in[31];
    const int* src = eidx;  // row 0 of edge_index

    float* out5 = (float*)d_out;
    float* att  = out5 + (size_t)N_GRAPHS_C * 5;

    char* p = (char*)d_ws;
    size_t off = 0;
    auto alloc = [&](size_t bytes) -> void* {
        void* r = p + off;
        off += (bytes + 255) & ~(size_t)255;
        return r;
    };
    int* cnt     = (int*)alloc((size_t)N_NODES_C * 4);
    int* rowptr  = (int*)alloc((size_t)(N_NODES_C + 1) * 4);
    int* growptr = (int*)alloc((size_t)(N_NODES_C + 1) * 4);
    int* work    = (int*)alloc((size_t)N_NODES_C * 4);
    int* epos    = (int*)alloc((size_t)N_EDGES_C * 4);
    int* grp     = (int*)alloc((size_t)(N_GRAPHS_C + 1) * 4);
    int* ngroups = (int*)alloc(256);
    int2* nmeta  = (int2*)alloc((size_t)N_NODES_C * 8);
    float* gate  = (float*)alloc((size_t)N_NODES_C * 4);
    float* emb   = (float*)alloc((size_t)N_GRAPHS_C * 128 * 4);
    float* bufP  = (float*)alloc((size_t)N_NODES_C * HDIM_C * 4);
    float* bufQ  = (float*)alloc((size_t)N_NODES_C * HDIM_C * 4);
    float* bufR  = (float*)alloc((size_t)N_NODES_C * HDIM_C * 4);
    _Float16* EAp = (_Float16*)alloc((size_t)MAXG_C * 768 * 2);

    hipMemsetAsync(cnt, 0, (size_t)N_NODES_C * 4, stream);

    int eblocks = (N_EDGES_C + 255) / 256;
    hist_kernel<<<eblocks, 256, 0, stream>>>(src, cnt);
    scan_kernel<<<1, 1024, 0, stream>>>(cnt, rowptr, work, growptr, ngroups);
    scatter_kernel<<<eblocks, 256, 0, stream>>>(src, work, epos);
    graph_misc<<<(N_NODES_C + 255) / 256, 256, 0, stream>>>(rowptr, growptr, batch, nmeta, grp);
    pad_zero<<<(N_NODES_C * 16 + 255) / 256, 256, 0, stream>>>(nmeta, EAp);
    permute_ea<<<(N_EDGES_C + 63) / 64, 256, 0, stream>>>(ea, src, epos, rowptr, growptr, EAp);

    dim3 ng((N_NODES_C + 63) / 64, 2);
    int egrid = 2048;

    // L1: x -> (Base=P, Root=Q); edge writes h1 into P
    node_gemm<<<ng, 256, 0, stream>>>(x, IN_DIM_C, W1n, IN_DIM_C + EDGE_DIM_C, b1n, W1r, b1r, bufP, bufQ);
    edge_mfma<<<egrid, 256, 0, stream>>>(EAp, nmeta, bufP, bufQ, W1n, IN_DIM_C, IN_DIM_C + EDGE_DIM_C, bufP);
    // L2: P -> (Base=Q, Root=R); edge writes h2 into Q
    node_gemm<<<ng, 256, 0, stream>>>(bufP, HDIM_C, W2n, HDIM_C + EDGE_DIM_C, b2n, W2r, b2r, bufQ, bufR);
    edge_mfma<<<egrid, 256, 0, stream>>>(EAp, nmeta, bufQ, bufR, W2n, HDIM_C, HDIM_C + EDGE_DIM_C, bufQ);
    // L3: Q -> (Base=P, Root=R); edge writes h3 into P
    node_gemm<<<ng, 256, 0, stream>>>(bufQ, HDIM_C, W3n, HDIM_C + EDGE_DIM_C, b3n, W3r, b3r, bufP, bufR);
    edge_mfma<<<egrid, 256, 0, stream>>>(EAp, nmeta, bufP, bufR, W3n, HDIM_C, HDIM_C + EDGE_DIM_C, bufP);

    gate_kernel<<<(N_NODES_C + 63) / 64, 256, 0, stream>>>(bufP, Wg1, bg1, Wg2, bg2, Wg3, bg3, gate);
    graph_attn<<<N_GRAPHS_C, 256, 0, stream>>>(gate, grp, bufP, att, emb);
    final_mlp<<<N_GRAPHS_C, 256, 0, stream>>>(emb, u_soap, u_dimer,
                                              Wl1, bl1, Wl2, bl2, Wl3, bl3, Wl, bl, out5);
}